// Round 1
// baseline (647.246 us; speedup 1.0000x reference)
//
#include <hip/hip_runtime.h>
#include <math.h>

#define N_NODES 20000
#define N_EDGES 320000
#define F_IN 40
#define T_TOW 5
#define EMB 40
#define NPB 8          // nodes per block in edge kernel -> 2500 blocks

// workspace byte offsets (all 64B-aligned)
#define WS_STATS   0          // S1[40], S2[40] float  (zeroed by memset)
#define WS_DEG     320        // int[N]                (zeroed by memset)
#define WS_ROWS    80384      // int[N+1]
#define WS_CURSOR  160512     // int[N]
#define WS_SSRC    240640     // int[E]
#define WS_AGG     1520640    // float[N*800]  (n, t, {mean,mn,mx,std}, g)
#define WS_POST    65520640   // float[N*40]
#define WS_H0      68720640   // float[N*40]

// ---------------- K1: in-degree count ----------------
__global__ __launch_bounds__(256) void k_count(const int* __restrict__ dst,
                                               int* __restrict__ deg) {
  int i = blockIdx.x * 256 + threadIdx.x;
  if (i < N_EDGES) atomicAdd(&deg[dst[i]], 1);
}

// ---------------- K2: exclusive scan (single block, 1024 thr x 20) ----------------
#define SCAN_CH 20
__global__ __launch_bounds__(1024) void k_scan(const int* __restrict__ deg,
                                               int* __restrict__ row_start,
                                               int* __restrict__ cursor) {
  const int tid = threadIdx.x;
  const int base = tid * SCAN_CH;
  int v[SCAN_CH];
  int run = 0;
#pragma unroll
  for (int j = 0; j < SCAN_CH; ++j) {
    int idx = base + j;
    int d = (idx < N_NODES) ? deg[idx] : 0;
    v[j] = d;
    run += d;
  }
  const int lane = tid & 63, wid = tid >> 6;
  int incl = run;
#pragma unroll
  for (int off = 1; off < 64; off <<= 1) {
    int y = __shfl_up(incl, off, 64);
    if (lane >= off) incl += y;
  }
  __shared__ int wtot[16];
  __shared__ int wpre[16];
  if (lane == 63) wtot[wid] = incl;
  __syncthreads();
  if (tid < 16) {
    int w = wtot[tid];
    int wi = w;
#pragma unroll
    for (int off = 1; off < 16; off <<= 1) {
      int y = __shfl_up(wi, off, 64);
      if (tid >= off) wi += y;
    }
    wpre[tid] = wi - w;  // exclusive prefix of wave totals
  }
  __syncthreads();
  int acc = incl - run + wpre[wid];  // exclusive prefix for this thread
#pragma unroll
  for (int j = 0; j < SCAN_CH; ++j) {
    int idx = base + j;
    if (idx < N_NODES) { row_start[idx] = acc; cursor[idx] = acc; }
    acc += v[j];
  }
  if (tid == 1023) row_start[N_NODES] = acc;  // == E
}

// ---------------- K3: scatter edges into CSR order ----------------
__global__ __launch_bounds__(256) void k_scatter(const int* __restrict__ src,
                                                 const int* __restrict__ dst,
                                                 int* __restrict__ cursor,
                                                 int* __restrict__ ssrc) {
  int i = blockIdx.x * 256 + threadIdx.x;
  if (i < N_EDGES) {
    int d = dst[i];
    int pos = atomicAdd(&cursor[d], 1);
    ssrc[pos] = src[i];
  }
}

// ---------------- K4: edge loop + per-(t,g) stats ----------------
// lane tc<200 owns (t,g); W_pre dst/src halves in 80 VGPRs; x rows fetched
// with wave-uniform float4 broadcast loads (x is L2-resident).
__global__ __launch_bounds__(256) void k_edge(const float* __restrict__ x,
                                              const int* __restrict__ row_start,
                                              const int* __restrict__ ssrc,
                                              const float* __restrict__ W_pre,
                                              const float* __restrict__ b_pre,
                                              float* __restrict__ agg) {
  const int tid = threadIdx.x;
  const int tc = tid < 200 ? tid : 199;
  const int t = tc / 40, g = tc - t * 40;
  const bool active = tid < 200;
  float wd[40], wsr[40];
  const float* Wt = W_pre + t * 3200;  // (80,40) per tower
#pragma unroll
  for (int j = 0; j < 40; ++j) {
    wd[j] = Wt[j * 40 + g];
    wsr[j] = Wt[(40 + j) * 40 + g];
  }
  const float bias = b_pre[t * 40 + g];

  const int n0 = blockIdx.x * NPB;
  for (int ni = 0; ni < NPB; ++ni) {
    const int n = n0 + ni;
    const float* xd = x + n * F_IN;
    float md = bias;
#pragma unroll
    for (int j = 0; j < 40; j += 4) {
      const float4 xv = *(const float4*)(xd + j);
      md += xv.x * wd[j] + xv.y * wd[j + 1] + xv.z * wd[j + 2] + xv.w * wd[j + 3];
    }
    const int r0 = row_start[n], r1 = row_start[n + 1];
    float sum = 0.f, ssq = 0.f, mn = 3.4e38f, mx = -3.4e38f;
    int s = (r0 < r1) ? ssrc[r0] : 0;
    for (int p = r0; p < r1; ++p) {
      const int sn = (p + 1 < r1) ? ssrc[p + 1] : 0;  // prefetch next src idx
      const float* xs = x + s * F_IN;
      float m = md;
#pragma unroll
      for (int j = 0; j < 40; j += 4) {
        const float4 xv = *(const float4*)(xs + j);
        m += xv.x * wsr[j] + xv.y * wsr[j + 1] + xv.z * wsr[j + 2] + xv.w * wsr[j + 3];
      }
      sum += m;
      ssq += m * m;
      mn = fminf(mn, m);
      mx = fmaxf(mx, m);
      s = sn;
    }
    const int cnt = r1 - r0;
    const float denom = fmaxf((float)cnt, 1.f);
    const float mean = sum / denom;
    const float mean2 = ssq / denom;
    const float sd = sqrtf(fmaxf(mean2 - mean * mean, 0.f) + 1e-5f);
    if (cnt == 0) { mn = 0.f; mx = 0.f; }
    if (active) {
      float* a = agg + n * 800 + t * 160 + g;
      a[0] = mean;    // j = g        (mean)
      a[40] = mn;     // j = 40+g     (min)
      a[80] = mx;     // j = 80+g     (max)
      a[120] = sd;    // j = 120+g    (std)
    }
  }
}

// ---------------- K5: post-MLP per (node, tower), scalers folded ----------------
__global__ __launch_bounds__(256) void k_post(const float* __restrict__ x,
                                              const float* __restrict__ agg,
                                              const int* __restrict__ row_start,
                                              const float* __restrict__ W_post,
                                              const float* __restrict__ b_post,
                                              const float* __restrict__ avg_dl,
                                              float* __restrict__ post) {
  const int u = blockIdx.x * 256 + threadIdx.x;
  if (u >= N_NODES * T_TOW) return;
  const int t = u / N_NODES;          // tower-major: wave-uniform t -> uniform W addrs
  const int n = u - t * N_NODES;
  const int cnt = row_start[n + 1] - row_start[n];
  const float degf = fmaxf((float)cnt, 1.f);
  const float logd = logf(degf + 1.f);
  const float avg = avg_dl[0];
  const float s1 = logd / avg, s2 = avg / logd;
  const float* Wt = W_post + t * (520 * 8);
  float acc[8];
#pragma unroll
  for (int g2 = 0; g2 < 8; ++g2) acc[g2] = b_post[t * 8 + g2];
  // x part: k = 0..39
  const float* xr = x + n * F_IN;
  for (int f = 0; f < 40; f += 4) {
    const float4 xv = *(const float4*)(xr + f);
    const float vv[4] = {xv.x, xv.y, xv.z, xv.w};
#pragma unroll
    for (int ff = 0; ff < 4; ++ff) {
      const float* w = Wt + (f + ff) * 8;
      const float4 w0 = *(const float4*)(w);
      const float4 w1 = *(const float4*)(w + 4);
      acc[0] += vv[ff] * w0.x; acc[1] += vv[ff] * w0.y;
      acc[2] += vv[ff] * w0.z; acc[3] += vv[ff] * w0.w;
      acc[4] += vv[ff] * w1.x; acc[5] += vv[ff] * w1.y;
      acc[6] += vv[ff] * w1.z; acc[7] += vv[ff] * w1.w;
    }
  }
  // agg part: k1=40+j (identity), k2=200+j (*s1), k3=360+j (*s2)
  const float* ar = agg + n * 800 + t * 160;
  for (int j = 0; j < 160; j += 4) {
    const float4 av = *(const float4*)(ar + j);
    const float vv[4] = {av.x, av.y, av.z, av.w};
#pragma unroll
    for (int jj = 0; jj < 4; ++jj) {
      const int kj = j + jj;
      const float4 a0 = *(const float4*)(Wt + (40 + kj) * 8);
      const float4 a1 = *(const float4*)(Wt + (40 + kj) * 8 + 4);
      const float4 b0 = *(const float4*)(Wt + (200 + kj) * 8);
      const float4 b1 = *(const float4*)(Wt + (200 + kj) * 8 + 4);
      const float4 c0 = *(const float4*)(Wt + (360 + kj) * 8);
      const float4 c1 = *(const float4*)(Wt + (360 + kj) * 8 + 4);
      const float vj = vv[jj];
      acc[0] += vj * (a0.x + s1 * b0.x + s2 * c0.x);
      acc[1] += vj * (a0.y + s1 * b0.y + s2 * c0.y);
      acc[2] += vj * (a0.z + s1 * b0.z + s2 * c0.z);
      acc[3] += vj * (a0.w + s1 * b0.w + s2 * c0.w);
      acc[4] += vj * (a1.x + s1 * b1.x + s2 * c1.x);
      acc[5] += vj * (a1.y + s1 * b1.y + s2 * c1.y);
      acc[6] += vj * (a1.z + s1 * b1.z + s2 * c1.z);
      acc[7] += vj * (a1.w + s1 * b1.w + s2 * c1.w);
    }
  }
  float* pr = post + n * 40 + t * 8;
#pragma unroll
  for (int g2 = 0; g2 < 8; ++g2) pr[g2] = acc[g2];
}

// ---------------- K6: W_lin mix + column sum/sumsq for GraphNorm ----------------
__global__ __launch_bounds__(256) void k_mix(const float* __restrict__ post,
                                             const float* __restrict__ W_lin,
                                             const float* __restrict__ b_lin,
                                             float* __restrict__ h0,
                                             float* __restrict__ S1,
                                             float* __restrict__ S2) {
  __shared__ float cs[EMB], cq[EMB];
  const int tid = threadIdx.x;
  if (tid < EMB) { cs[tid] = 0.f; cq[tid] = 0.f; }
  __syncthreads();
  const int n = blockIdx.x * 256 + tid;
  const bool ok = n < N_NODES;
  float acc[EMB];
#pragma unroll
  for (int e = 0; e < EMB; e += 4) {
    const float4 b = *(const float4*)(b_lin + e);
    acc[e] = b.x; acc[e + 1] = b.y; acc[e + 2] = b.z; acc[e + 3] = b.w;
  }
  const int nn = ok ? n : 0;
  const float* pr = post + nn * 40;
  for (int k = 0; k < 40; k += 4) {
    const float4 pv = *(const float4*)(pr + k);
    const float pp[4] = {pv.x, pv.y, pv.z, pv.w};
#pragma unroll
    for (int kk = 0; kk < 4; ++kk) {
      const float* w = W_lin + (k + kk) * EMB;
#pragma unroll
      for (int e = 0; e < EMB; e += 4) {
        const float4 wv = *(const float4*)(w + e);
        acc[e] += pp[kk] * wv.x; acc[e + 1] += pp[kk] * wv.y;
        acc[e + 2] += pp[kk] * wv.z; acc[e + 3] += pp[kk] * wv.w;
      }
    }
  }
  if (ok) {
    float* hr = h0 + n * EMB;
#pragma unroll
    for (int e = 0; e < EMB; ++e) {
      hr[e] = acc[e];
      atomicAdd(&cs[e], acc[e]);
      atomicAdd(&cq[e], acc[e] * acc[e]);
    }
  }
  __syncthreads();
  if (tid < EMB) {
    atomicAdd(&S1[tid], cs[tid]);
    atomicAdd(&S2[tid], cq[tid]);
  }
}

// ---------------- K7: GraphNorm + ReLU + W1 + ReLU + W2 ----------------
__global__ __launch_bounds__(256) void k_head(const float* __restrict__ h0,
                                              const float* __restrict__ S1,
                                              const float* __restrict__ S2,
                                              const float* __restrict__ gn_w,
                                              const float* __restrict__ gn_b,
                                              const float* __restrict__ gn_ms,
                                              const float* __restrict__ W1,
                                              const float* __restrict__ b1,
                                              const float* __restrict__ W2,
                                              const float* __restrict__ b2,
                                              float* __restrict__ out) {
  const int n = blockIdx.x * 256 + threadIdx.x;
  if (n >= N_NODES) return;
  const float invN = 1.f / (float)N_NODES;
  float v[EMB];
  const float* hr = h0 + n * EMB;
#pragma unroll
  for (int e = 0; e < EMB; ++e) {
    const float M = S1[e] * invN;
    const float ms = gn_ms[e];
    const float var = S2[e] * invN - ms * (2.f - ms) * M * M;
    const float sc = gn_w[e] / sqrtf(var + 1e-5f);
    v[e] = fmaxf((hr[e] - ms * M) * sc + gn_b[e], 0.f);
  }
  float h1[EMB];
#pragma unroll
  for (int e = 0; e < EMB; ++e) h1[e] = b1[e];
  for (int k = 0; k < EMB; ++k) {
    const float vk = v[k];
    const float* w = W1 + k * EMB;
#pragma unroll
    for (int e = 0; e < EMB; e += 4) {
      const float4 wv = *(const float4*)(w + e);
      h1[e] += vk * wv.x; h1[e + 1] += vk * wv.y;
      h1[e + 2] += vk * wv.z; h1[e + 3] += vk * wv.w;
    }
  }
  float o0 = b2[0], o1 = b2[1];
#pragma unroll
  for (int k = 0; k < EMB; ++k) {
    const float r = fmaxf(h1[k], 0.f);
    o0 = fmaf(r, W2[k * 2], o0);
    o1 = fmaf(r, W2[k * 2 + 1], o1);
  }
  out[n * 2] = o0;
  out[n * 2 + 1] = o1;
}

extern "C" void kernel_launch(void* const* d_in, const int* in_sizes, int n_in,
                              void* d_out, int out_size, void* d_ws, size_t ws_size,
                              hipStream_t stream) {
  const float* x      = (const float*)d_in[0];
  const int*   ei     = (const int*)d_in[1];
  const float* W_pre  = (const float*)d_in[2];
  const float* b_pre  = (const float*)d_in[3];
  const float* W_post = (const float*)d_in[4];
  const float* b_post = (const float*)d_in[5];
  const float* W_lin  = (const float*)d_in[6];
  const float* b_lin  = (const float*)d_in[7];
  const float* gn_w   = (const float*)d_in[8];
  const float* gn_b   = (const float*)d_in[9];
  const float* gn_ms  = (const float*)d_in[10];
  const float* W1     = (const float*)d_in[11];
  const float* b1     = (const float*)d_in[12];
  const float* W2     = (const float*)d_in[13];
  const float* b2     = (const float*)d_in[14];
  const float* avg_dl = (const float*)d_in[15];
  float* out = (float*)d_out;

  char* ws = (char*)d_ws;
  float* S1   = (float*)(ws + WS_STATS);
  float* S2   = S1 + 40;
  int* deg    = (int*)(ws + WS_DEG);
  int* rows   = (int*)(ws + WS_ROWS);
  int* cursor = (int*)(ws + WS_CURSOR);
  int* ssrc   = (int*)(ws + WS_SSRC);
  float* agg  = (float*)(ws + WS_AGG);
  float* post = (float*)(ws + WS_POST);
  float* h0   = (float*)(ws + WS_H0);
  const int* e_src = ei;
  const int* e_dst = ei + N_EDGES;

  hipMemsetAsync(ws, 0, 80320, stream);  // zero S1,S2,deg
  k_count<<<(N_EDGES + 255) / 256, 256, 0, stream>>>(e_dst, deg);
  k_scan<<<1, 1024, 0, stream>>>(deg, rows, cursor);
  k_scatter<<<(N_EDGES + 255) / 256, 256, 0, stream>>>(e_src, e_dst, cursor, ssrc);
  k_edge<<<N_NODES / NPB, 256, 0, stream>>>(x, rows, ssrc, W_pre, b_pre, agg);
  k_post<<<(N_NODES * T_TOW + 255) / 256, 256, 0, stream>>>(x, agg, rows, W_post,
                                                            b_post, avg_dl, post);
  k_mix<<<(N_NODES + 255) / 256, 256, 0, stream>>>(post, W_lin, b_lin, h0, S1, S2);
  k_head<<<(N_NODES + 255) / 256, 256, 0, stream>>>(h0, S1, S2, gn_w, gn_b, gn_ms,
                                                    W1, b1, W2, b2, out);
}

// Round 2
// 497.604 us; speedup vs baseline: 1.3007x; 1.3007x over previous
//
#include <hip/hip_runtime.h>
#include <math.h>

#define N_NODES 20000
#define N_EDGES 320000
#define F_IN 40
#define T_TOW 5
#define EMB 40
#define NPB 4           // nodes per block in edge kernel -> 5000 blocks
#define NPB_PRE 16      // nodes per block in projection kernel -> 1250 blocks

typedef __attribute__((ext_vector_type(8))) _Float16 half8;

// workspace byte offsets (all 64B-aligned)
#define WS_STATS   0          // S1[40], S2[40] float  (zeroed by memset)
#define WS_DEG     320        // int[N]                (zeroed by memset)
#define WS_ROWS    80384      // int[N+1]
#define WS_CURSOR  160448     // int[N]
#define WS_SSRC    240512     // int[E]
#define WS_MS      1520640    // half[N*200] src-projection
#define WS_MD      9520640    // half[N*200] dst-projection (+bias)
#define WS_AGG     17520640   // half[N*800]  (n, t, {mean,mn,mx,std}, g)
#define WS_POST    49520640   // float[N*40]
#define WS_H0      52720640   // float[N*40]

// ---------------- K1: in-degree count ----------------
__global__ __launch_bounds__(256) void k_count(const int* __restrict__ dst,
                                               int* __restrict__ deg) {
  int i = blockIdx.x * 256 + threadIdx.x;
  if (i < N_EDGES) atomicAdd(&deg[dst[i]], 1);
}

// ---------------- K2: exclusive scan (single block, 1024 thr x 20) ----------------
#define SCAN_CH 20
__global__ __launch_bounds__(1024) void k_scan(const int* __restrict__ deg,
                                               int* __restrict__ row_start,
                                               int* __restrict__ cursor) {
  const int tid = threadIdx.x;
  const int base = tid * SCAN_CH;
  int v[SCAN_CH];
  int run = 0;
#pragma unroll
  for (int j = 0; j < SCAN_CH; ++j) {
    int idx = base + j;
    int d = (idx < N_NODES) ? deg[idx] : 0;
    v[j] = d;
    run += d;
  }
  const int lane = tid & 63, wid = tid >> 6;
  int incl = run;
#pragma unroll
  for (int off = 1; off < 64; off <<= 1) {
    int y = __shfl_up(incl, off, 64);
    if (lane >= off) incl += y;
  }
  __shared__ int wtot[16];
  __shared__ int wpre[16];
  if (lane == 63) wtot[wid] = incl;
  __syncthreads();
  if (tid < 16) {
    int w = wtot[tid];
    int wi = w;
#pragma unroll
    for (int off = 1; off < 16; off <<= 1) {
      int y = __shfl_up(wi, off, 64);
      if (tid >= off) wi += y;
    }
    wpre[tid] = wi - w;  // exclusive prefix of wave totals
  }
  __syncthreads();
  int acc = incl - run + wpre[wid];  // exclusive prefix for this thread
#pragma unroll
  for (int j = 0; j < SCAN_CH; ++j) {
    int idx = base + j;
    if (idx < N_NODES) { row_start[idx] = acc; cursor[idx] = acc; }
    acc += v[j];
  }
  if (tid == 1023) row_start[N_NODES] = acc;  // == E
}

// ---------------- K3: scatter edges into CSR order ----------------
__global__ __launch_bounds__(256) void k_scatter(const int* __restrict__ src,
                                                 const int* __restrict__ dst,
                                                 int* __restrict__ cursor,
                                                 int* __restrict__ ssrc) {
  int i = blockIdx.x * 256 + threadIdx.x;
  if (i < N_EDGES) {
    int d = dst[i];
    int pos = atomicAdd(&cursor[d], 1);
    ssrc[pos] = src[i];
  }
}

// ---------------- K_pre: per-node projections ms = x.Wsrc, md = bias + x.Wdst ---
// lane tc<200 owns (t,g); W columns in 80 VGPRs; x rows via wave-uniform float4.
__global__ __launch_bounds__(256) void k_pre(const float* __restrict__ x,
                                             const float* __restrict__ W_pre,
                                             const float* __restrict__ b_pre,
                                             _Float16* __restrict__ mS,
                                             _Float16* __restrict__ mD) {
  const int tid = threadIdx.x;
  const int tc = tid < 200 ? tid : 199;
  const int t = tc / 40, g = tc - t * 40;
  const bool active = tid < 200;
  float wd[40], wsr[40];
  const float* Wt = W_pre + t * 3200;  // (80,40) per tower
#pragma unroll
  for (int j = 0; j < 40; ++j) {
    wd[j] = Wt[j * 40 + g];
    wsr[j] = Wt[(40 + j) * 40 + g];
  }
  const float bias = b_pre[t * 40 + g];
  const int n0 = blockIdx.x * NPB_PRE;
  for (int ni = 0; ni < NPB_PRE; ++ni) {
    const int n = n0 + ni;
    const float* xr = x + n * F_IN;
    float md = bias, ms = 0.f;
#pragma unroll
    for (int j = 0; j < 40; j += 4) {
      const float4 xv = *(const float4*)(xr + j);
      md += xv.x * wd[j] + xv.y * wd[j + 1] + xv.z * wd[j + 2] + xv.w * wd[j + 3];
      ms += xv.x * wsr[j] + xv.y * wsr[j + 1] + xv.z * wsr[j + 2] + xv.w * wsr[j + 3];
    }
    if (active) {
      mD[n * 200 + tc] = (_Float16)md;
      mS[n * 200 + tc] = (_Float16)ms;
    }
  }
}

// ---------------- K4: edge loop = 1 fp16 load + stats per edge per lane --------
__global__ __launch_bounds__(256) void k_edge(const _Float16* __restrict__ mS,
                                              const _Float16* __restrict__ mD,
                                              const int* __restrict__ row_start,
                                              const int* __restrict__ ssrc,
                                              _Float16* __restrict__ agg) {
  const int tid = threadIdx.x;
  const int tc = tid < 200 ? tid : 199;
  const bool active = tid < 200;
  const int n0 = blockIdx.x * NPB;
  for (int ni = 0; ni < NPB; ++ni) {
    const int n = n0 + ni;
    const int r0 = row_start[n], r1 = row_start[n + 1];
    const float md = (float)mD[n * 200 + tc];
    float sum = 0.f, ssq = 0.f, mn = 3.4e38f, mx = -3.4e38f;
    // depth-3 software pipeline on the ms-row loads
    int sa = (r0 < r1) ? ssrc[r0] : 0;
    int sb = (r0 + 1 < r1) ? ssrc[r0 + 1] : 0;
    _Float16 ha = mS[sa * 200 + tc];
    _Float16 hb = mS[sb * 200 + tc];
    for (int p = r0; p < r1; ++p) {
      const int sc2 = (p + 2 < r1) ? ssrc[p + 2] : 0;
      const _Float16 hc = mS[sc2 * 200 + tc];
      const float v = (float)ha;
      sum += v;
      ssq += v * v;
      mn = fminf(mn, v);
      mx = fmaxf(mx, v);
      ha = hb;
      hb = hc;
    }
    const int cnt = r1 - r0;
    float mean, sd;
    if (cnt > 0) {
      const float inv = 1.f / (float)cnt;
      const float ms_mean = sum * inv;
      const float var = ssq * inv - ms_mean * ms_mean;
      sd = sqrtf(fmaxf(var, 0.f) + 1e-5f);
      mean = md + ms_mean;
      mn = md + mn;
      mx = md + mx;
    } else {
      mean = 0.f; mn = 0.f; mx = 0.f; sd = sqrtf(1e-5f);
    }
    if (active) {
      const int t = tc / 40, g = tc - t * 40;
      _Float16* a = agg + n * 800 + t * 160 + g;
      a[0] = (_Float16)mean;
      a[40] = (_Float16)mn;
      a[80] = (_Float16)mx;
      a[120] = (_Float16)sd;
    }
  }
}

// ---------------- K5: post-MLP per (node, tower), scalers folded ----------------
__global__ __launch_bounds__(256) void k_post(const float* __restrict__ x,
                                              const _Float16* __restrict__ agg,
                                              const int* __restrict__ row_start,
                                              const float* __restrict__ W_post,
                                              const float* __restrict__ b_post,
                                              const float* __restrict__ avg_dl,
                                              float* __restrict__ post) {
  const int u = blockIdx.x * 256 + threadIdx.x;
  if (u >= N_NODES * T_TOW) return;
  const int t = u / N_NODES;          // tower-major: wave-uniform t -> uniform W addrs
  const int n = u - t * N_NODES;
  const int cnt = row_start[n + 1] - row_start[n];
  const float degf = fmaxf((float)cnt, 1.f);
  const float logd = logf(degf + 1.f);
  const float avg = avg_dl[0];
  const float s1 = logd / avg, s2 = avg / logd;
  const float* Wt = W_post + t * (520 * 8);
  float acc[8];
#pragma unroll
  for (int g2 = 0; g2 < 8; ++g2) acc[g2] = b_post[t * 8 + g2];
  // x part: k = 0..39
  const float* xr = x + n * F_IN;
  for (int f = 0; f < 40; f += 4) {
    const float4 xv = *(const float4*)(xr + f);
    const float vv[4] = {xv.x, xv.y, xv.z, xv.w};
#pragma unroll
    for (int ff = 0; ff < 4; ++ff) {
      const float* w = Wt + (f + ff) * 8;
      const float4 w0 = *(const float4*)(w);
      const float4 w1 = *(const float4*)(w + 4);
      acc[0] += vv[ff] * w0.x; acc[1] += vv[ff] * w0.y;
      acc[2] += vv[ff] * w0.z; acc[3] += vv[ff] * w0.w;
      acc[4] += vv[ff] * w1.x; acc[5] += vv[ff] * w1.y;
      acc[6] += vv[ff] * w1.z; acc[7] += vv[ff] * w1.w;
    }
  }
  // agg part: k1=40+j (identity), k2=200+j (*s1), k3=360+j (*s2)
  const _Float16* ar = agg + n * 800 + t * 160;
  for (int j = 0; j < 160; j += 8) {
    const half8 av = *(const half8*)(ar + j);
#pragma unroll
    for (int jj = 0; jj < 8; ++jj) {
      const int kj = j + jj;
      const float4 a0 = *(const float4*)(Wt + (40 + kj) * 8);
      const float4 a1 = *(const float4*)(Wt + (40 + kj) * 8 + 4);
      const float4 b0 = *(const float4*)(Wt + (200 + kj) * 8);
      const float4 b1 = *(const float4*)(Wt + (200 + kj) * 8 + 4);
      const float4 c0 = *(const float4*)(Wt + (360 + kj) * 8);
      const float4 c1 = *(const float4*)(Wt + (360 + kj) * 8 + 4);
      const float vj = (float)av[jj];
      acc[0] += vj * (a0.x + s1 * b0.x + s2 * c0.x);
      acc[1] += vj * (a0.y + s1 * b0.y + s2 * c0.y);
      acc[2] += vj * (a0.z + s1 * b0.z + s2 * c0.z);
      acc[3] += vj * (a0.w + s1 * b0.w + s2 * c0.w);
      acc[4] += vj * (a1.x + s1 * b1.x + s2 * c1.x);
      acc[5] += vj * (a1.y + s1 * b1.y + s2 * c1.y);
      acc[6] += vj * (a1.z + s1 * b1.z + s2 * c1.z);
      acc[7] += vj * (a1.w + s1 * b1.w + s2 * c1.w);
    }
  }
  float* pr = post + n * 40 + t * 8;
#pragma unroll
  for (int g2 = 0; g2 < 8; ++g2) pr[g2] = acc[g2];
}

// ---------------- K6: W_lin mix + column sum/sumsq for GraphNorm ----------------
__global__ __launch_bounds__(256) void k_mix(const float* __restrict__ post,
                                             const float* __restrict__ W_lin,
                                             const float* __restrict__ b_lin,
                                             float* __restrict__ h0,
                                             float* __restrict__ S1,
                                             float* __restrict__ S2) {
  __shared__ float cs[EMB], cq[EMB];
  const int tid = threadIdx.x;
  if (tid < EMB) { cs[tid] = 0.f; cq[tid] = 0.f; }
  __syncthreads();
  const int n = blockIdx.x * 256 + tid;
  const bool ok = n < N_NODES;
  float acc[EMB];
#pragma unroll
  for (int e = 0; e < EMB; e += 4) {
    const float4 b = *(const float4*)(b_lin + e);
    acc[e] = b.x; acc[e + 1] = b.y; acc[e + 2] = b.z; acc[e + 3] = b.w;
  }
  const int nn = ok ? n : 0;
  const float* pr = post + nn * 40;
  for (int k = 0; k < 40; k += 4) {
    const float4 pv = *(const float4*)(pr + k);
    const float pp[4] = {pv.x, pv.y, pv.z, pv.w};
#pragma unroll
    for (int kk = 0; kk < 4; ++kk) {
      const float* w = W_lin + (k + kk) * EMB;
#pragma unroll
      for (int e = 0; e < EMB; e += 4) {
        const float4 wv = *(const float4*)(w + e);
        acc[e] += pp[kk] * wv.x; acc[e + 1] += pp[kk] * wv.y;
        acc[e + 2] += pp[kk] * wv.z; acc[e + 3] += pp[kk] * wv.w;
      }
    }
  }
  if (ok) {
    float* hr = h0 + n * EMB;
#pragma unroll
    for (int e = 0; e < EMB; ++e) {
      hr[e] = acc[e];
      atomicAdd(&cs[e], acc[e]);
      atomicAdd(&cq[e], acc[e] * acc[e]);
    }
  }
  __syncthreads();
  if (tid < EMB) {
    atomicAdd(&S1[tid], cs[tid]);
    atomicAdd(&S2[tid], cq[tid]);
  }
}

// ---------------- K7: GraphNorm + ReLU + W1 + ReLU + W2 ----------------
__global__ __launch_bounds__(256) void k_head(const float* __restrict__ h0,
                                              const float* __restrict__ S1,
                                              const float* __restrict__ S2,
                                              const float* __restrict__ gn_w,
                                              const float* __restrict__ gn_b,
                                              const float* __restrict__ gn_ms,
                                              const float* __restrict__ W1,
                                              const float* __restrict__ b1,
                                              const float* __restrict__ W2,
                                              const float* __restrict__ b2,
                                              float* __restrict__ out) {
  const int n = blockIdx.x * 256 + threadIdx.x;
  if (n >= N_NODES) return;
  const float invN = 1.f / (float)N_NODES;
  float v[EMB];
  const float* hr = h0 + n * EMB;
#pragma unroll
  for (int e = 0; e < EMB; ++e) {
    const float M = S1[e] * invN;
    const float ms = gn_ms[e];
    const float var = S2[e] * invN - ms * (2.f - ms) * M * M;
    const float sc = gn_w[e] / sqrtf(var + 1e-5f);
    v[e] = fmaxf((hr[e] - ms * M) * sc + gn_b[e], 0.f);
  }
  float h1[EMB];
#pragma unroll
  for (int e = 0; e < EMB; ++e) h1[e] = b1[e];
  for (int k = 0; k < EMB; ++k) {
    const float vk = v[k];
    const float* w = W1 + k * EMB;
#pragma unroll
    for (int e = 0; e < EMB; e += 4) {
      const float4 wv = *(const float4*)(w + e);
      h1[e] += vk * wv.x; h1[e + 1] += vk * wv.y;
      h1[e + 2] += vk * wv.z; h1[e + 3] += vk * wv.w;
    }
  }
  float o0 = b2[0], o1 = b2[1];
#pragma unroll
  for (int k = 0; k < EMB; ++k) {
    const float r = fmaxf(h1[k], 0.f);
    o0 = fmaf(r, W2[k * 2], o0);
    o1 = fmaf(r, W2[k * 2 + 1], o1);
  }
  out[n * 2] = o0;
  out[n * 2 + 1] = o1;
}

extern "C" void kernel_launch(void* const* d_in, const int* in_sizes, int n_in,
                              void* d_out, int out_size, void* d_ws, size_t ws_size,
                              hipStream_t stream) {
  const float* x      = (const float*)d_in[0];
  const int*   ei     = (const int*)d_in[1];
  const float* W_pre  = (const float*)d_in[2];
  const float* b_pre  = (const float*)d_in[3];
  const float* W_post = (const float*)d_in[4];
  const float* b_post = (const float*)d_in[5];
  const float* W_lin  = (const float*)d_in[6];
  const float* b_lin  = (const float*)d_in[7];
  const float* gn_w   = (const float*)d_in[8];
  const float* gn_b   = (const float*)d_in[9];
  const float* gn_ms  = (const float*)d_in[10];
  const float* W1     = (const float*)d_in[11];
  const float* b1     = (const float*)d_in[12];
  const float* W2     = (const float*)d_in[13];
  const float* b2     = (const float*)d_in[14];
  const float* avg_dl = (const float*)d_in[15];
  float* out = (float*)d_out;

  char* ws = (char*)d_ws;
  float* S1   = (float*)(ws + WS_STATS);
  float* S2   = S1 + 40;
  int* deg    = (int*)(ws + WS_DEG);
  int* rows   = (int*)(ws + WS_ROWS);
  int* cursor = (int*)(ws + WS_CURSOR);
  int* ssrc   = (int*)(ws + WS_SSRC);
  _Float16* mS  = (_Float16*)(ws + WS_MS);
  _Float16* mD  = (_Float16*)(ws + WS_MD);
  _Float16* agg = (_Float16*)(ws + WS_AGG);
  float* post = (float*)(ws + WS_POST);
  float* h0   = (float*)(ws + WS_H0);
  const int* e_src = ei;
  const int* e_dst = ei + N_EDGES;

  hipMemsetAsync(ws, 0, 80320, stream);  // zero S1,S2,deg
  k_pre<<<N_NODES / NPB_PRE, 256, 0, stream>>>(x, W_pre, b_pre, mS, mD);
  k_count<<<(N_EDGES + 255) / 256, 256, 0, stream>>>(e_dst, deg);
  k_scan<<<1, 1024, 0, stream>>>(deg, rows, cursor);
  k_scatter<<<(N_EDGES + 255) / 256, 256, 0, stream>>>(e_src, e_dst, cursor, ssrc);
  k_edge<<<N_NODES / NPB, 256, 0, stream>>>(mS, mD, rows, ssrc, agg);
  k_post<<<(N_NODES * T_TOW + 255) / 256, 256, 0, stream>>>(x, agg, rows, W_post,
                                                            b_post, avg_dl, post);
  k_mix<<<(N_NODES + 255) / 256, 256, 0, stream>>>(post, W_lin, b_lin, h0, S1, S2);
  k_head<<<(N_NODES + 255) / 256, 256, 0, stream>>>(h0, S1, S2, gn_w, gn_b, gn_ms,
                                                    W1, b1, W2, b2, out);
}

// Round 4
// 473.905 us; speedup vs baseline: 1.3658x; 1.0500x over previous
//
#include <hip/hip_runtime.h>
#include <math.h>

#define N_NODES 20000
#define N_EDGES 320000
#define F_IN 40
#define T_TOW 5
#define EMB 40
#define NPB 4           // nodes per block in edge kernel -> 5000 blocks
#define NPB_PRE 16      // nodes per block in projection kernel -> 1250 blocks

typedef __attribute__((ext_vector_type(8))) _Float16 half8;

// workspace byte offsets (all 64B-aligned)
#define WS_STATS   0          // S1[40], S2[40] float  (zeroed by memset)
#define WS_DEG     320        // int[N]                (zeroed by memset)
#define WS_ROWS    80384      // int[N+1]
#define WS_CURSOR  160448     // int[N]
#define WS_SSRC    240512     // int[E]
#define WS_MS      1520640    // half[N*200] src-projection
#define WS_MD      9520640    // half[N*200] dst-projection (+bias)
#define WS_AGG     17520640   // half[N*800]  (n, t, {mean,mn,mx,std}, g)
#define WS_POST    49520640   // float[N*40]
#define WS_H0      52720640   // float[N*40]

// ---------------- K1: in-degree count ----------------
__global__ __launch_bounds__(256) void k_count(const int* __restrict__ dst,
                                               int* __restrict__ deg) {
  int i = blockIdx.x * 256 + threadIdx.x;
  if (i < N_EDGES) atomicAdd(&deg[dst[i]], 1);
}

// ---------------- K2: exclusive scan (single block, 1024 thr x 20) ----------------
#define SCAN_CH 20
__global__ __launch_bounds__(1024) void k_scan(const int* __restrict__ deg,
                                               int* __restrict__ row_start,
                                               int* __restrict__ cursor) {
  const int tid = threadIdx.x;
  const int base = tid * SCAN_CH;
  int v[SCAN_CH];
  int run = 0;
#pragma unroll
  for (int j = 0; j < SCAN_CH; ++j) {
    int idx = base + j;
    int d = (idx < N_NODES) ? deg[idx] : 0;
    v[j] = d;
    run += d;
  }
  const int lane = tid & 63, wid = tid >> 6;
  int incl = run;
#pragma unroll
  for (int off = 1; off < 64; off <<= 1) {
    int y = __shfl_up(incl, off, 64);
    if (lane >= off) incl += y;
  }
  __shared__ int wtot[16];
  __shared__ int wpre[16];
  if (lane == 63) wtot[wid] = incl;
  __syncthreads();
  if (tid < 16) {
    int w = wtot[tid];
    int wi = w;
#pragma unroll
    for (int off = 1; off < 16; off <<= 1) {
      int y = __shfl_up(wi, off, 64);
      if (tid >= off) wi += y;
    }
    wpre[tid] = wi - w;  // exclusive prefix of wave totals
  }
  __syncthreads();
  int acc = incl - run + wpre[wid];  // exclusive prefix for this thread
#pragma unroll
  for (int j = 0; j < SCAN_CH; ++j) {
    int idx = base + j;
    if (idx < N_NODES) { row_start[idx] = acc; cursor[idx] = acc; }
    acc += v[j];
  }
  if (tid == 1023) row_start[N_NODES] = acc;  // == E
}

// ---------------- K3: scatter edges into CSR order ----------------
__global__ __launch_bounds__(256) void k_scatter(const int* __restrict__ src,
                                                 const int* __restrict__ dst,
                                                 int* __restrict__ cursor,
                                                 int* __restrict__ ssrc) {
  int i = blockIdx.x * 256 + threadIdx.x;
  if (i < N_EDGES) {
    int d = dst[i];
    int pos = atomicAdd(&cursor[d], 1);
    ssrc[pos] = src[i];
  }
}

// ---------------- K_pre: per-node projections ms = x.Wsrc, md = bias + x.Wdst ---
__global__ __launch_bounds__(256) void k_pre(const float* __restrict__ x,
                                             const float* __restrict__ W_pre,
                                             const float* __restrict__ b_pre,
                                             _Float16* __restrict__ mS,
                                             _Float16* __restrict__ mD) {
  const int tid = threadIdx.x;
  const int tc = tid < 200 ? tid : 199;
  const int t = tc / 40, g = tc - t * 40;
  const bool active = tid < 200;
  float wd[40], wsr[40];
  const float* Wt = W_pre + t * 3200;  // (80,40) per tower
#pragma unroll
  for (int j = 0; j < 40; ++j) {
    wd[j] = Wt[j * 40 + g];
    wsr[j] = Wt[(40 + j) * 40 + g];
  }
  const float bias = b_pre[t * 40 + g];
  const int n0 = blockIdx.x * NPB_PRE;
  for (int ni = 0; ni < NPB_PRE; ++ni) {
    const int n = n0 + ni;
    const float* xr = x + n * F_IN;
    float md = bias, ms = 0.f;
#pragma unroll
    for (int j = 0; j < 40; j += 4) {
      const float4 xv = *(const float4*)(xr + j);
      md += xv.x * wd[j] + xv.y * wd[j + 1] + xv.z * wd[j + 2] + xv.w * wd[j + 3];
      ms += xv.x * wsr[j] + xv.y * wsr[j + 1] + xv.z * wsr[j + 2] + xv.w * wsr[j + 3];
    }
    if (active) {
      mD[n * 200 + tc] = (_Float16)md;
      mS[n * 200 + tc] = (_Float16)ms;
    }
  }
}

// ---------------- K4: edge loop = 1 fp16 load + stats per edge per lane --------
__global__ __launch_bounds__(256) void k_edge(const _Float16* __restrict__ mS,
                                              const _Float16* __restrict__ mD,
                                              const int* __restrict__ row_start,
                                              const int* __restrict__ ssrc,
                                              _Float16* __restrict__ agg) {
  const int tid = threadIdx.x;
  const int tc = tid < 200 ? tid : 199;
  const bool active = tid < 200;
  const int n0 = blockIdx.x * NPB;
  for (int ni = 0; ni < NPB; ++ni) {
    const int n = n0 + ni;
    const int r0 = row_start[n], r1 = row_start[n + 1];
    const float md = (float)mD[n * 200 + tc];
    float sum = 0.f, ssq = 0.f, mn = 3.4e38f, mx = -3.4e38f;
    int sa = (r0 < r1) ? ssrc[r0] : 0;
    int sb = (r0 + 1 < r1) ? ssrc[r0 + 1] : 0;
    _Float16 ha = mS[sa * 200 + tc];
    _Float16 hb = mS[sb * 200 + tc];
    for (int p = r0; p < r1; ++p) {
      const int sc2 = (p + 2 < r1) ? ssrc[p + 2] : 0;
      const _Float16 hc = mS[sc2 * 200 + tc];
      const float v = (float)ha;
      sum += v;
      ssq += v * v;
      mn = fminf(mn, v);
      mx = fmaxf(mx, v);
      ha = hb;
      hb = hc;
    }
    const int cnt = r1 - r0;
    float mean, sd;
    if (cnt > 0) {
      const float inv = 1.f / (float)cnt;
      const float ms_mean = sum * inv;
      const float var = ssq * inv - ms_mean * ms_mean;
      sd = sqrtf(fmaxf(var, 0.f) + 1e-5f);
      mean = md + ms_mean;
      mn = md + mn;
      mx = md + mx;
    } else {
      mean = 0.f; mn = 0.f; mx = 0.f; sd = sqrtf(1e-5f);
    }
    if (active) {
      const int t = tc / 40, g = tc - t * 40;
      _Float16* a = agg + n * 800 + t * 160 + g;
      a[0] = (_Float16)mean;
      a[40] = (_Float16)mn;
      a[80] = (_Float16)mx;
      a[120] = (_Float16)sd;
    }
  }
}

// ---------------- K5: post-MLP per (node, tower), scalers folded ----------------
__global__ __launch_bounds__(256) void k_post(const float* __restrict__ x,
                                              const _Float16* __restrict__ agg,
                                              const int* __restrict__ row_start,
                                              const float* __restrict__ W_post,
                                              const float* __restrict__ b_post,
                                              const float* __restrict__ avg_dl,
                                              float* __restrict__ post) {
  const int u = blockIdx.x * 256 + threadIdx.x;
  if (u >= N_NODES * T_TOW) return;
  const int t = u / N_NODES;          // tower-major: wave-uniform t -> uniform W addrs
  const int n = u - t * N_NODES;
  const int cnt = row_start[n + 1] - row_start[n];
  const float degf = fmaxf((float)cnt, 1.f);
  const float logd = logf(degf + 1.f);
  const float avg = avg_dl[0];
  const float s1 = logd / avg, s2 = avg / logd;
  const float* Wt = W_post + t * (520 * 8);
  float acc[8];
#pragma unroll
  for (int g2 = 0; g2 < 8; ++g2) acc[g2] = b_post[t * 8 + g2];
  // x part: k = 0..39
  const float* xr = x + n * F_IN;
  for (int f = 0; f < 40; f += 4) {
    const float4 xv = *(const float4*)(xr + f);
    const float vv[4] = {xv.x, xv.y, xv.z, xv.w};
#pragma unroll
    for (int ff = 0; ff < 4; ++ff) {
      const float* w = Wt + (f + ff) * 8;
      const float4 w0 = *(const float4*)(w);
      const float4 w1 = *(const float4*)(w + 4);
      acc[0] += vv[ff] * w0.x; acc[1] += vv[ff] * w0.y;
      acc[2] += vv[ff] * w0.z; acc[3] += vv[ff] * w0.w;
      acc[4] += vv[ff] * w1.x; acc[5] += vv[ff] * w1.y;
      acc[6] += vv[ff] * w1.z; acc[7] += vv[ff] * w1.w;
    }
  }
  // agg part: k1=40+j (identity), k2=200+j (*s1), k3=360+j (*s2)
  const _Float16* ar = agg + n * 800 + t * 160;
  for (int j = 0; j < 160; j += 8) {
    const half8 av = *(const half8*)(ar + j);
#pragma unroll
    for (int jj = 0; jj < 8; ++jj) {
      const int kj = j + jj;
      const float4 a0 = *(const float4*)(Wt + (40 + kj) * 8);
      const float4 a1 = *(const float4*)(Wt + (40 + kj) * 8 + 4);
      const float4 b0 = *(const float4*)(Wt + (200 + kj) * 8);
      const float4 b1 = *(const float4*)(Wt + (200 + kj) * 8 + 4);
      const float4 c0 = *(const float4*)(Wt + (360 + kj) * 8);
      const float4 c1 = *(const float4*)(Wt + (360 + kj) * 8 + 4);
      const float vj = (float)av[jj];
      acc[0] += vj * (a0.x + s1 * b0.x + s2 * c0.x);
      acc[1] += vj * (a0.y + s1 * b0.y + s2 * c0.y);
      acc[2] += vj * (a0.z + s1 * b0.z + s2 * c0.z);
      acc[3] += vj * (a0.w + s1 * b0.w + s2 * c0.w);
      acc[4] += vj * (a1.x + s1 * b1.x + s2 * c1.x);
      acc[5] += vj * (a1.y + s1 * b1.y + s2 * c1.y);
      acc[6] += vj * (a1.z + s1 * b1.z + s2 * c1.z);
      acc[7] += vj * (a1.w + s1 * b1.w + s2 * c1.w);
    }
  }
  float* pr = post + n * 40 + t * 8;
#pragma unroll
  for (int g2 = 0; g2 < 8; ++g2) pr[g2] = acc[g2];
}

// ---------------- K6: W_lin mix + GraphNorm column stats ----------------
// 256 thr / 4 waves: lane = node (64 nodes per block); wave w handles
// 8-col chunks {w, w+4 (<5)}. 8 named accumulators per chunk -> no spill.
// Stats: per-chunk shuffle butterfly over the 64 node-lanes, lane 0 does
// 16 global float atomics.
__global__ __launch_bounds__(256) void k_mix(const float* __restrict__ post,
                                             const float* __restrict__ W_lin,
                                             const float* __restrict__ b_lin,
                                             float* __restrict__ h0,
                                             float* __restrict__ S1,
                                             float* __restrict__ S2) {
  const int wv = threadIdx.x >> 6;       // 0..3
  const int lane = threadIdx.x & 63;
  const int n = blockIdx.x * 64 + lane;
  const bool ok = n < N_NODES;
  const int nn = ok ? n : 0;
  const float* pr = post + nn * 40;
  for (int c = wv; c < 5; c += 4) {      // wave 0: chunks 0,4; waves 1-3: 1..3
    const int c0 = c * 8;
    const float4 bb0 = *(const float4*)(b_lin + c0);
    const float4 bb1 = *(const float4*)(b_lin + c0 + 4);
    float a0 = bb0.x, a1 = bb0.y, a2 = bb0.z, a3 = bb0.w;
    float a4 = bb1.x, a5 = bb1.y, a6 = bb1.z, a7 = bb1.w;
    for (int k = 0; k < 40; k += 4) {
      const float4 pv = *(const float4*)(pr + k);
      const float pp[4] = {pv.x, pv.y, pv.z, pv.w};
#pragma unroll
      for (int kk = 0; kk < 4; ++kk) {
        const float* w = W_lin + (k + kk) * EMB + c0;
        const float4 w0 = *(const float4*)(w);
        const float4 w1 = *(const float4*)(w + 4);
        const float p = pp[kk];
        a0 = fmaf(p, w0.x, a0); a1 = fmaf(p, w0.y, a1);
        a2 = fmaf(p, w0.z, a2); a3 = fmaf(p, w0.w, a3);
        a4 = fmaf(p, w1.x, a4); a5 = fmaf(p, w1.y, a5);
        a6 = fmaf(p, w1.z, a6); a7 = fmaf(p, w1.w, a7);
      }
    }
    if (ok) {
      float4 o0 = {a0, a1, a2, a3}, o1 = {a4, a5, a6, a7};
      *(float4*)(h0 + n * 40 + c0) = o0;
      *(float4*)(h0 + n * 40 + c0 + 4) = o1;
    } else {
      a0 = a1 = a2 = a3 = a4 = a5 = a6 = a7 = 0.f;
    }
    float s[8] = {a0, a1, a2, a3, a4, a5, a6, a7};
#pragma unroll
    for (int j = 0; j < 8; ++j) {
      float sv = s[j], qv = s[j] * s[j];
#pragma unroll
      for (int m = 32; m >= 1; m >>= 1) {
        sv += __shfl_xor(sv, m, 64);
        qv += __shfl_xor(qv, m, 64);
      }
      if (lane == 0) {
        atomicAdd(&S1[c0 + j], sv);
        atomicAdd(&S2[c0 + j], qv);
      }
    }
  }
}

// ---------------- K7: GraphNorm + ReLU + W1 + ReLU + W2 ----------------
__global__ __launch_bounds__(256) void k_head(const float* __restrict__ h0,
                                              const float* __restrict__ S1,
                                              const float* __restrict__ S2,
                                              const float* __restrict__ gn_w,
                                              const float* __restrict__ gn_b,
                                              const float* __restrict__ gn_ms,
                                              const float* __restrict__ W1,
                                              const float* __restrict__ b1,
                                              const float* __restrict__ W2,
                                              const float* __restrict__ b2,
                                              float* __restrict__ out) {
  const int n = blockIdx.x * 256 + threadIdx.x;
  if (n >= N_NODES) return;
  const float invN = 1.f / (float)N_NODES;
  float v[EMB];
  const float* hr = h0 + n * EMB;
#pragma unroll
  for (int e = 0; e < EMB; ++e) {
    const float M = S1[e] * invN;
    const float ms = gn_ms[e];
    const float var = S2[e] * invN - ms * (2.f - ms) * M * M;
    const float sc = gn_w[e] / sqrtf(var + 1e-5f);
    v[e] = fmaxf((hr[e] - ms * M) * sc + gn_b[e], 0.f);
  }
  float h1[EMB];
#pragma unroll
  for (int e = 0; e < EMB; ++e) h1[e] = b1[e];
  for (int k = 0; k < EMB; ++k) {
    const float vk = v[k];
    const float* w = W1 + k * EMB;
#pragma unroll
    for (int e = 0; e < EMB; e += 4) {
      const float4 wv = *(const float4*)(w + e);
      h1[e] += vk * wv.x; h1[e + 1] += vk * wv.y;
      h1[e + 2] += vk * wv.z; h1[e + 3] += vk * wv.w;
    }
  }
  float o0 = b2[0], o1 = b2[1];
#pragma unroll
  for (int k = 0; k < EMB; ++k) {
    const float r = fmaxf(h1[k], 0.f);
    o0 = fmaf(r, W2[k * 2], o0);
    o1 = fmaf(r, W2[k * 2 + 1], o1);
  }
  out[n * 2] = o0;
  out[n * 2 + 1] = o1;
}

extern "C" void kernel_launch(void* const* d_in, const int* in_sizes, int n_in,
                              void* d_out, int out_size, void* d_ws, size_t ws_size,
                              hipStream_t stream) {
  const float* x      = (const float*)d_in[0];
  const int*   ei     = (const int*)d_in[1];
  const float* W_pre  = (const float*)d_in[2];
  const float* b_pre  = (const float*)d_in[3];
  const float* W_post = (const float*)d_in[4];
  const float* b_post = (const float*)d_in[5];
  const float* W_lin  = (const float*)d_in[6];
  const float* b_lin  = (const float*)d_in[7];
  const float* gn_w   = (const float*)d_in[8];
  const float* gn_b   = (const float*)d_in[9];
  const float* gn_ms  = (const float*)d_in[10];
  const float* W1     = (const float*)d_in[11];
  const float* b1     = (const float*)d_in[12];
  const float* W2     = (const float*)d_in[13];
  const float* b2     = (const float*)d_in[14];
  const float* avg_dl = (const float*)d_in[15];
  float* out = (float*)d_out;

  char* ws = (char*)d_ws;
  float* S1   = (float*)(ws + WS_STATS);
  float* S2   = S1 + 40;
  int* deg    = (int*)(ws + WS_DEG);
  int* rows   = (int*)(ws + WS_ROWS);
  int* cursor = (int*)(ws + WS_CURSOR);
  int* ssrc   = (int*)(ws + WS_SSRC);
  _Float16* mS  = (_Float16*)(ws + WS_MS);
  _Float16* mD  = (_Float16*)(ws + WS_MD);
  _Float16* agg = (_Float16*)(ws + WS_AGG);
  float* post = (float*)(ws + WS_POST);
  float* h0   = (float*)(ws + WS_H0);
  const int* e_src = ei;
  const int* e_dst = ei + N_EDGES;

  hipMemsetAsync(ws, 0, 80320, stream);  // zero S1,S2,deg
  k_pre<<<N_NODES / NPB_PRE, 256, 0, stream>>>(x, W_pre, b_pre, mS, mD);
  k_count<<<(N_EDGES + 255) / 256, 256, 0, stream>>>(e_dst, deg);
  k_scan<<<1, 1024, 0, stream>>>(deg, rows, cursor);
  k_scatter<<<(N_EDGES + 255) / 256, 256, 0, stream>>>(e_src, e_dst, cursor, ssrc);
  k_edge<<<N_NODES / NPB, 256, 0, stream>>>(mS, mD, rows, ssrc, agg);
  k_post<<<(N_NODES * T_TOW + 255) / 256, 256, 0, stream>>>(x, agg, rows, W_post,
                                                            b_post, avg_dl, post);
  k_mix<<<(N_NODES + 63) / 64, 256, 0, stream>>>(post, W_lin, b_lin, h0, S1, S2);
  k_head<<<(N_NODES + 255) / 256, 256, 0, stream>>>(h0, S1, S2, gn_w, gn_b, gn_ms,
                                                    W1, b1, W2, b2, out);
}

// Round 5
// 360.321 us; speedup vs baseline: 1.7963x; 1.3152x over previous
//
#include <hip/hip_runtime.h>
#include <math.h>

#define N_NODES 20000
#define N_EDGES 320000
#define F_IN 40
#define T_TOW 5
#define EMB 40
#define NPB 4           // nodes per block in edge kernel -> 5000 blocks
#define NPB_PRE 16      // nodes per block in projection kernel -> 1250 blocks
#define NBLK_MIX 313    // ceil(20000/64)

typedef __attribute__((ext_vector_type(8))) _Float16 half8;

// workspace byte offsets (all 64B-aligned)
#define WS_STATS   0          // S1[40], S2[40] float  (written by k_stats)
#define WS_DEG     320        // int[N]                (zeroed by memset)
#define WS_ROWS    80384      // int[N+1]
#define WS_CURSOR  160448     // int[N]
#define WS_SSRC    240512     // int[E]
#define WS_MS      1520640    // half[N*200] src-projection
#define WS_MD      9520640    // half[N*200] dst-projection (+bias)
#define WS_AGG     17520640   // half[N*800]  (n, t, {mean,mn,mx,std}, g)
#define WS_POST    49520640   // float[N*40]
#define WS_H0      52720640   // float[N*40]
#define WS_PART    55920640   // float[NBLK_MIX*80] per-block stat partials

// ---------------- K1: in-degree count ----------------
__global__ __launch_bounds__(256) void k_count(const int* __restrict__ dst,
                                               int* __restrict__ deg) {
  int i = blockIdx.x * 256 + threadIdx.x;
  if (i < N_EDGES) atomicAdd(&deg[dst[i]], 1);
}

// ---------------- K2: exclusive scan (single block, 1024 thr x 20) ----------------
#define SCAN_CH 20
__global__ __launch_bounds__(1024) void k_scan(const int* __restrict__ deg,
                                               int* __restrict__ row_start,
                                               int* __restrict__ cursor) {
  const int tid = threadIdx.x;
  const int base = tid * SCAN_CH;
  int v[SCAN_CH];
  int run = 0;
#pragma unroll
  for (int j = 0; j < SCAN_CH; ++j) {
    int idx = base + j;
    int d = (idx < N_NODES) ? deg[idx] : 0;
    v[j] = d;
    run += d;
  }
  const int lane = tid & 63, wid = tid >> 6;
  int incl = run;
#pragma unroll
  for (int off = 1; off < 64; off <<= 1) {
    int y = __shfl_up(incl, off, 64);
    if (lane >= off) incl += y;
  }
  __shared__ int wtot[16];
  __shared__ int wpre[16];
  if (lane == 63) wtot[wid] = incl;
  __syncthreads();
  if (tid < 16) {
    int w = wtot[tid];
    int wi = w;
#pragma unroll
    for (int off = 1; off < 16; off <<= 1) {
      int y = __shfl_up(wi, off, 64);
      if (tid >= off) wi += y;
    }
    wpre[tid] = wi - w;  // exclusive prefix of wave totals
  }
  __syncthreads();
  int acc = incl - run + wpre[wid];  // exclusive prefix for this thread
#pragma unroll
  for (int j = 0; j < SCAN_CH; ++j) {
    int idx = base + j;
    if (idx < N_NODES) { row_start[idx] = acc; cursor[idx] = acc; }
    acc += v[j];
  }
  if (tid == 1023) row_start[N_NODES] = acc;  // == E
}

// ---------------- K3: scatter edges into CSR order ----------------
__global__ __launch_bounds__(256) void k_scatter(const int* __restrict__ src,
                                                 const int* __restrict__ dst,
                                                 int* __restrict__ cursor,
                                                 int* __restrict__ ssrc) {
  int i = blockIdx.x * 256 + threadIdx.x;
  if (i < N_EDGES) {
    int d = dst[i];
    int pos = atomicAdd(&cursor[d], 1);
    ssrc[pos] = src[i];
  }
}

// ---------------- K_pre: per-node projections ms = x.Wsrc, md = bias + x.Wdst ---
__global__ __launch_bounds__(256) void k_pre(const float* __restrict__ x,
                                             const float* __restrict__ W_pre,
                                             const float* __restrict__ b_pre,
                                             _Float16* __restrict__ mS,
                                             _Float16* __restrict__ mD) {
  const int tid = threadIdx.x;
  const int tc = tid < 200 ? tid : 199;
  const int t = tc / 40, g = tc - t * 40;
  const bool active = tid < 200;
  float wd[40], wsr[40];
  const float* Wt = W_pre + t * 3200;  // (80,40) per tower
#pragma unroll
  for (int j = 0; j < 40; ++j) {
    wd[j] = Wt[j * 40 + g];
    wsr[j] = Wt[(40 + j) * 40 + g];
  }
  const float bias = b_pre[t * 40 + g];
  const int n0 = blockIdx.x * NPB_PRE;
  for (int ni = 0; ni < NPB_PRE; ++ni) {
    const int n = n0 + ni;
    const float* xr = x + n * F_IN;
    float md = bias, ms = 0.f;
#pragma unroll
    for (int j = 0; j < 40; j += 4) {
      const float4 xv = *(const float4*)(xr + j);
      md += xv.x * wd[j] + xv.y * wd[j + 1] + xv.z * wd[j + 2] + xv.w * wd[j + 3];
      ms += xv.x * wsr[j] + xv.y * wsr[j + 1] + xv.z * wsr[j + 2] + xv.w * wsr[j + 3];
    }
    if (active) {
      mD[n * 200 + tc] = (_Float16)md;
      mS[n * 200 + tc] = (_Float16)ms;
    }
  }
}

// ---------------- K4: edge loop = 1 fp16 load + stats per edge per lane --------
__global__ __launch_bounds__(256) void k_edge(const _Float16* __restrict__ mS,
                                              const _Float16* __restrict__ mD,
                                              const int* __restrict__ row_start,
                                              const int* __restrict__ ssrc,
                                              _Float16* __restrict__ agg) {
  const int tid = threadIdx.x;
  const int tc = tid < 200 ? tid : 199;
  const bool active = tid < 200;
  const int n0 = blockIdx.x * NPB;
  for (int ni = 0; ni < NPB; ++ni) {
    const int n = n0 + ni;
    const int r0 = row_start[n], r1 = row_start[n + 1];
    const float md = (float)mD[n * 200 + tc];
    float sum = 0.f, ssq = 0.f, mn = 3.4e38f, mx = -3.4e38f;
    int sa = (r0 < r1) ? ssrc[r0] : 0;
    int sb = (r0 + 1 < r1) ? ssrc[r0 + 1] : 0;
    _Float16 ha = mS[sa * 200 + tc];
    _Float16 hb = mS[sb * 200 + tc];
    for (int p = r0; p < r1; ++p) {
      const int sc2 = (p + 2 < r1) ? ssrc[p + 2] : 0;
      const _Float16 hc = mS[sc2 * 200 + tc];
      const float v = (float)ha;
      sum += v;
      ssq += v * v;
      mn = fminf(mn, v);
      mx = fmaxf(mx, v);
      ha = hb;
      hb = hc;
    }
    const int cnt = r1 - r0;
    float mean, sd;
    if (cnt > 0) {
      const float inv = 1.f / (float)cnt;
      const float ms_mean = sum * inv;
      const float var = ssq * inv - ms_mean * ms_mean;
      sd = sqrtf(fmaxf(var, 0.f) + 1e-5f);
      mean = md + ms_mean;
      mn = md + mn;
      mx = md + mx;
    } else {
      mean = 0.f; mn = 0.f; mx = 0.f; sd = sqrtf(1e-5f);
    }
    if (active) {
      const int t = tc / 40, g = tc - t * 40;
      _Float16* a = agg + n * 800 + t * 160 + g;
      a[0] = (_Float16)mean;
      a[40] = (_Float16)mn;
      a[80] = (_Float16)mx;
      a[120] = (_Float16)sd;
    }
  }
}

// ---------------- K5: post-MLP per (node, tower), scalers folded ----------------
__global__ __launch_bounds__(256) void k_post(const float* __restrict__ x,
                                              const _Float16* __restrict__ agg,
                                              const int* __restrict__ row_start,
                                              const float* __restrict__ W_post,
                                              const float* __restrict__ b_post,
                                              const float* __restrict__ avg_dl,
                                              float* __restrict__ post) {
  const int u = blockIdx.x * 256 + threadIdx.x;
  if (u >= N_NODES * T_TOW) return;
  const int t = u / N_NODES;          // tower-major: wave-uniform t -> uniform W addrs
  const int n = u - t * N_NODES;
  const int cnt = row_start[n + 1] - row_start[n];
  const float degf = fmaxf((float)cnt, 1.f);
  const float logd = logf(degf + 1.f);
  const float avg = avg_dl[0];
  const float s1 = logd / avg, s2 = avg / logd;
  const float* Wt = W_post + t * (520 * 8);
  float acc[8];
#pragma unroll
  for (int g2 = 0; g2 < 8; ++g2) acc[g2] = b_post[t * 8 + g2];
  // x part: k = 0..39
  const float* xr = x + n * F_IN;
  for (int f = 0; f < 40; f += 4) {
    const float4 xv = *(const float4*)(xr + f);
    const float vv[4] = {xv.x, xv.y, xv.z, xv.w};
#pragma unroll
    for (int ff = 0; ff < 4; ++ff) {
      const float* w = Wt + (f + ff) * 8;
      const float4 w0 = *(const float4*)(w);
      const float4 w1 = *(const float4*)(w + 4);
      acc[0] += vv[ff] * w0.x; acc[1] += vv[ff] * w0.y;
      acc[2] += vv[ff] * w0.z; acc[3] += vv[ff] * w0.w;
      acc[4] += vv[ff] * w1.x; acc[5] += vv[ff] * w1.y;
      acc[6] += vv[ff] * w1.z; acc[7] += vv[ff] * w1.w;
    }
  }
  // agg part: k1=40+j (identity), k2=200+j (*s1), k3=360+j (*s2)
  const _Float16* ar = agg + n * 800 + t * 160;
  for (int j = 0; j < 160; j += 8) {
    const half8 av = *(const half8*)(ar + j);
#pragma unroll
    for (int jj = 0; jj < 8; ++jj) {
      const int kj = j + jj;
      const float4 a0 = *(const float4*)(Wt + (40 + kj) * 8);
      const float4 a1 = *(const float4*)(Wt + (40 + kj) * 8 + 4);
      const float4 b0 = *(const float4*)(Wt + (200 + kj) * 8);
      const float4 b1 = *(const float4*)(Wt + (200 + kj) * 8 + 4);
      const float4 c0 = *(const float4*)(Wt + (360 + kj) * 8);
      const float4 c1 = *(const float4*)(Wt + (360 + kj) * 8 + 4);
      const float vj = (float)av[jj];
      acc[0] += vj * (a0.x + s1 * b0.x + s2 * c0.x);
      acc[1] += vj * (a0.y + s1 * b0.y + s2 * c0.y);
      acc[2] += vj * (a0.z + s1 * b0.z + s2 * c0.z);
      acc[3] += vj * (a0.w + s1 * b0.w + s2 * c0.w);
      acc[4] += vj * (a1.x + s1 * b1.x + s2 * c1.x);
      acc[5] += vj * (a1.y + s1 * b1.y + s2 * c1.y);
      acc[6] += vj * (a1.z + s1 * b1.z + s2 * c1.z);
      acc[7] += vj * (a1.w + s1 * b1.w + s2 * c1.w);
    }
  }
  float* pr = post + n * 40 + t * 8;
#pragma unroll
  for (int g2 = 0; g2 < 8; ++g2) pr[g2] = acc[g2];
}

// ---------------- K6: W_lin mix + per-block stat partials (no atomics) --------
// 256 thr / 4 waves: lane = node (64 nodes per block); wave w handles
// 8-col chunks {w, w+4 (<5)}. After the 64-lane butterfly, lane 0 STORES the
// block's partial sums to partial[block][80] (40 sum + 40 sumsq).
__global__ __launch_bounds__(256) void k_mix(const float* __restrict__ post,
                                             const float* __restrict__ W_lin,
                                             const float* __restrict__ b_lin,
                                             float* __restrict__ h0,
                                             float* __restrict__ partial) {
  const int wv = threadIdx.x >> 6;       // 0..3
  const int lane = threadIdx.x & 63;
  const int n = blockIdx.x * 64 + lane;
  const bool ok = n < N_NODES;
  const int nn = ok ? n : 0;
  const float* pr = post + nn * 40;
  for (int c = wv; c < 5; c += 4) {      // wave 0: chunks 0,4; waves 1-3: 1..3
    const int c0 = c * 8;
    const float4 bb0 = *(const float4*)(b_lin + c0);
    const float4 bb1 = *(const float4*)(b_lin + c0 + 4);
    float a0 = bb0.x, a1 = bb0.y, a2 = bb0.z, a3 = bb0.w;
    float a4 = bb1.x, a5 = bb1.y, a6 = bb1.z, a7 = bb1.w;
    for (int k = 0; k < 40; k += 4) {
      const float4 pv = *(const float4*)(pr + k);
      const float pp[4] = {pv.x, pv.y, pv.z, pv.w};
#pragma unroll
      for (int kk = 0; kk < 4; ++kk) {
        const float* w = W_lin + (k + kk) * EMB + c0;
        const float4 w0 = *(const float4*)(w);
        const float4 w1 = *(const float4*)(w + 4);
        const float p = pp[kk];
        a0 = fmaf(p, w0.x, a0); a1 = fmaf(p, w0.y, a1);
        a2 = fmaf(p, w0.z, a2); a3 = fmaf(p, w0.w, a3);
        a4 = fmaf(p, w1.x, a4); a5 = fmaf(p, w1.y, a5);
        a6 = fmaf(p, w1.z, a6); a7 = fmaf(p, w1.w, a7);
      }
    }
    if (ok) {
      float4 o0 = {a0, a1, a2, a3}, o1 = {a4, a5, a6, a7};
      *(float4*)(h0 + n * 40 + c0) = o0;
      *(float4*)(h0 + n * 40 + c0 + 4) = o1;
    } else {
      a0 = a1 = a2 = a3 = a4 = a5 = a6 = a7 = 0.f;
    }
    float s[8] = {a0, a1, a2, a3, a4, a5, a6, a7};
#pragma unroll
    for (int j = 0; j < 8; ++j) {
      float sv = s[j], qv = s[j] * s[j];
#pragma unroll
      for (int m = 32; m >= 1; m >>= 1) {
        sv += __shfl_xor(sv, m, 64);
        qv += __shfl_xor(qv, m, 64);
      }
      if (lane == 0) {
        partial[blockIdx.x * 80 + c0 + j] = sv;
        partial[blockIdx.x * 80 + 40 + c0 + j] = qv;
      }
    }
  }
}

// ---------------- K6b: reduce partials -> S1[40], S2[40] ----------------
// 80 blocks x 64 lanes: block = column (0..39 sum, 40..79 sumsq);
// lane sums its strided share of the 313 block-partials, butterfly, store.
__global__ __launch_bounds__(64) void k_stats(const float* __restrict__ partial,
                                              float* __restrict__ S1,
                                              float* __restrict__ S2) {
  const int col = blockIdx.x;            // 0..79
  const int lane = threadIdx.x;
  float s = 0.f;
  for (int b = lane; b < NBLK_MIX; b += 64) s += partial[b * 80 + col];
#pragma unroll
  for (int m = 32; m >= 1; m >>= 1) s += __shfl_xor(s, m, 64);
  if (lane == 0) {
    if (col < 40) S1[col] = s;
    else S2[col - 40] = s;
  }
}

// ---------------- K7: GraphNorm + ReLU + W1 + ReLU + W2 ----------------
__global__ __launch_bounds__(256) void k_head(const float* __restrict__ h0,
                                              const float* __restrict__ S1,
                                              const float* __restrict__ S2,
                                              const float* __restrict__ gn_w,
                                              const float* __restrict__ gn_b,
                                              const float* __restrict__ gn_ms,
                                              const float* __restrict__ W1,
                                              const float* __restrict__ b1,
                                              const float* __restrict__ W2,
                                              const float* __restrict__ b2,
                                              float* __restrict__ out) {
  const int n = blockIdx.x * 256 + threadIdx.x;
  if (n >= N_NODES) return;
  const float invN = 1.f / (float)N_NODES;
  float v[EMB];
  const float* hr = h0 + n * EMB;
#pragma unroll
  for (int e = 0; e < EMB; ++e) {
    const float M = S1[e] * invN;
    const float ms = gn_ms[e];
    const float var = S2[e] * invN - ms * (2.f - ms) * M * M;
    const float sc = gn_w[e] / sqrtf(var + 1e-5f);
    v[e] = fmaxf((hr[e] - ms * M) * sc + gn_b[e], 0.f);
  }
  float h1[EMB];
#pragma unroll
  for (int e = 0; e < EMB; ++e) h1[e] = b1[e];
  for (int k = 0; k < EMB; ++k) {
    const float vk = v[k];
    const float* w = W1 + k * EMB;
#pragma unroll
    for (int e = 0; e < EMB; e += 4) {
      const float4 wv = *(const float4*)(w + e);
      h1[e] += vk * wv.x; h1[e + 1] += vk * wv.y;
      h1[e + 2] += vk * wv.z; h1[e + 3] += vk * wv.w;
    }
  }
  float o0 = b2[0], o1 = b2[1];
#pragma unroll
  for (int k = 0; k < EMB; ++k) {
    const float r = fmaxf(h1[k], 0.f);
    o0 = fmaf(r, W2[k * 2], o0);
    o1 = fmaf(r, W2[k * 2 + 1], o1);
  }
  out[n * 2] = o0;
  out[n * 2 + 1] = o1;
}

extern "C" void kernel_launch(void* const* d_in, const int* in_sizes, int n_in,
                              void* d_out, int out_size, void* d_ws, size_t ws_size,
                              hipStream_t stream) {
  const float* x      = (const float*)d_in[0];
  const int*   ei     = (const int*)d_in[1];
  const float* W_pre  = (const float*)d_in[2];
  const float* b_pre  = (const float*)d_in[3];
  const float* W_post = (const float*)d_in[4];
  const float* b_post = (const float*)d_in[5];
  const float* W_lin  = (const float*)d_in[6];
  const float* b_lin  = (const float*)d_in[7];
  const float* gn_w   = (const float*)d_in[8];
  const float* gn_b   = (const float*)d_in[9];
  const float* gn_ms  = (const float*)d_in[10];
  const float* W1     = (const float*)d_in[11];
  const float* b1     = (const float*)d_in[12];
  const float* W2     = (const float*)d_in[13];
  const float* b2     = (const float*)d_in[14];
  const float* avg_dl = (const float*)d_in[15];
  float* out = (float*)d_out;

  char* ws = (char*)d_ws;
  float* S1   = (float*)(ws + WS_STATS);
  float* S2   = S1 + 40;
  int* deg    = (int*)(ws + WS_DEG);
  int* rows   = (int*)(ws + WS_ROWS);
  int* cursor = (int*)(ws + WS_CURSOR);
  int* ssrc   = (int*)(ws + WS_SSRC);
  _Float16* mS  = (_Float16*)(ws + WS_MS);
  _Float16* mD  = (_Float16*)(ws + WS_MD);
  _Float16* agg = (_Float16*)(ws + WS_AGG);
  float* post = (float*)(ws + WS_POST);
  float* h0   = (float*)(ws + WS_H0);
  float* part = (float*)(ws + WS_PART);
  const int* e_src = ei;
  const int* e_dst = ei + N_EDGES;

  hipMemsetAsync(ws, 0, 80320, stream);  // zero deg (S1/S2 now plain-written)
  k_pre<<<N_NODES / NPB_PRE, 256, 0, stream>>>(x, W_pre, b_pre, mS, mD);
  k_count<<<(N_EDGES + 255) / 256, 256, 0, stream>>>(e_dst, deg);
  k_scan<<<1, 1024, 0, stream>>>(deg, rows, cursor);
  k_scatter<<<(N_EDGES + 255) / 256, 256, 0, stream>>>(e_src, e_dst, cursor, ssrc);
  k_edge<<<N_NODES / NPB, 256, 0, stream>>>(mS, mD, rows, ssrc, agg);
  k_post<<<(N_NODES * T_TOW + 255) / 256, 256, 0, stream>>>(x, agg, rows, W_post,
                                                            b_post, avg_dl, post);
  k_mix<<<NBLK_MIX, 256, 0, stream>>>(post, W_lin, b_lin, h0, part);
  k_stats<<<80, 64, 0, stream>>>(part, S1, S2);
  k_head<<<(N_NODES + 255) / 256, 256, 0, stream>>>(h0, S1, S2, gn_w, gn_b, gn_ms,
                                                    W1, b1, W2, b2, out);
}